// Round 5
// baseline (53.275 us; speedup 1.0000x reference)
//
#include <hip/hip_runtime.h>
#include <hip/hip_bf16.h>

// Problem constants (from reference): B=16, N2=1024, N3=2048, D=128
#define NB   16
#define N2   1024
#define N3   2048
#define DD   128
#define OROWS (N3 + 1)   // 2049
#define OCOLS (N2 + 1)   // 1025

typedef __attribute__((ext_vector_type(8))) __bf16 bf16x8;
typedef __attribute__((ext_vector_type(4))) float  f32x4;

// Pack two f32 into one u32 of 2x bf16 (RNE). a -> low half, b -> high half.
static __device__ __forceinline__ unsigned pack_bf16x2(float a, float b) {
    unsigned ua = __float_as_uint(a);
    ua = (ua + 0x7FFF + ((ua >> 16) & 1)) >> 16;
    unsigned ub = __float_as_uint(b);
    ub = (ub + 0x7FFF + ((ub >> 16) & 1)) & 0xFFFF0000u;
    return ua | ub;
}

// Fully fused normalize + batched GEMM + pad, ONE kernel, ONE barrier total.
// One block = one 128(M) x 1024(N) output slab. Grid = 256 = 1 block/CU.
// A: reg-stage f32 -> row norm (shfl 1,2) -> bf16 -> swizzled LDS -> hoist to
//    registers once (prologue; the only __syncthreads in the kernel).
// B: NO LDS. The 16x16x32 MFMA B-fragment is 8 consecutive k-elems per lane,
//    so each lane loads its own B row segment (32 f32) straight from global
//    (L2-resident via XCD swizzle), row-norms via shfl_xor(16,32) across the
//    kq groups, converts in-register, MFMAs. No in-loop barriers/waitcnt asm:
//    stores are never waited on and stream continuously at HBM pace while
//    waves free-run.
__global__ __launch_bounds__(512, 1)
void fused_kernel(const float* __restrict__ d2,   // [NB*N2, 128] f32
                  const float* __restrict__ d3,   // [NB*N3, 128] f32
                  float* __restrict__ out) {
    __shared__ __align__(16) char smem[32768];    // A tile only

    // Bijective XCD swizzle: 256 blocks = 8 XCDs x 32; each XCD owns 2 whole
    // batches -> B f32 panels (1 MB) stay L2-resident per XCD.
    const int hw  = blockIdx.x;
    const int blk = (hw & 7) * 32 + (hw >> 3);
    const int b   = blk >> 4;           // batch
    const int ti  = blk & 15;           // M tile (128 rows of N3=2048)
    const int t   = threadIdx.x;

    const int wid = t >> 6;             // 8 waves
    const int l   = t & 63;
    const int wm  = (wid >> 2) * 64;    // 0 / 64  : wave's M offset
    const int wn  = (wid & 3) * 16;     // 0..48   : wave's N offset in 64-col chunk
    const int lr  = l & 15;
    const int kq  = l >> 4;
    const int sw  = (lr & 7) << 4;

    const float* gA  = d3 + ((size_t)(b * N3 + ti * 128)) * DD;
    const float* gB  = d2 + ((size_t)b * N2) * DD;
    // Lane's B address: row (wn+lr) of chunk 0, k-elems kq*8..(+8) per ks.
    const float* gBl = gB + (size_t)(wn + lr) * DD + kq * 8;

    // ---- Prologue: A loads ----
    const int arow  = t >> 2;           // 0..127
    const int apart = t & 3;            // 32-f32 part
    float4 av[8];
    #pragma unroll
    for (int i = 0; i < 8; ++i)
        av[i] = *reinterpret_cast<const float4*>(gA + (size_t)arow * DD + apart * 32 + i * 4);

    // B chunk 0 loads issued early (retire during A processing + barrier).
    float4 bva[8], bvb[8];
    #pragma unroll
    for (int ks = 0; ks < 4; ++ks) {
        bva[ks * 2]     = *reinterpret_cast<const float4*>(gBl + ks * 32);
        bva[ks * 2 + 1] = *reinterpret_cast<const float4*>(gBl + ks * 32 + 4);
    }

    // A: norm (reduce over the 4 lanes sharing a row) -> bf16 -> swizzled LDS.
    {
        float ss = 0.f;
        #pragma unroll
        for (int i = 0; i < 8; ++i)
            ss += av[i].x * av[i].x + av[i].y * av[i].y + av[i].z * av[i].z + av[i].w * av[i].w;
        ss += __shfl_xor(ss, 1);
        ss += __shfl_xor(ss, 2);
        const float s = rsqrtf(ss);
        const int aswz = (arow & 7) << 4;
        #pragma unroll
        for (int j = 0; j < 4; ++j) {
            uint4 w;
            w.x = pack_bf16x2(av[2 * j].x * s,     av[2 * j].y * s);
            w.y = pack_bf16x2(av[2 * j].z * s,     av[2 * j].w * s);
            w.z = pack_bf16x2(av[2 * j + 1].x * s, av[2 * j + 1].y * s);
            w.w = pack_bf16x2(av[2 * j + 1].z * s, av[2 * j + 1].w * s);
            int colb = apart * 64 + j * 16;
            *reinterpret_cast<uint4*>(smem + arow * 256 + (colb ^ aswz)) = w;
        }
    }
    __syncthreads();   // the ONLY barrier in the kernel

    // Hoist A fragments to registers (LDS not touched afterwards).
    bf16x8 af[4][4];   // [ks][mi]
    #pragma unroll
    for (int ks = 0; ks < 4; ++ks) {
        const int kb = ks * 64 + kq * 16;
        #pragma unroll
        for (int mi = 0; mi < 4; ++mi) {
            int r = wm + mi * 16 + lr;
            af[ks][mi] = *reinterpret_cast<const bf16x8*>(smem + r * 256 + (kb ^ sw));
        }
    }

    float* obase = out + (size_t)b * OROWS * OCOLS + (size_t)(ti * 128) * OCOLS;

    auto loadB = [&](float4 (&dst)[8], int nj) {
        const float* p = gBl + (size_t)nj * 64 * DD;
        #pragma unroll
        for (int ks = 0; ks < 4; ++ks) {
            dst[ks * 2]     = *reinterpret_cast<const float4*>(p + ks * 32);
            dst[ks * 2 + 1] = *reinterpret_cast<const float4*>(p + ks * 32 + 4);
        }
    };

    auto process = [&](const float4 (&bv)[8], int nj) {
        // Row norm: own 32 elems + combine the 4 kq groups (lanes ^16, ^32).
        float ss = 0.f;
        #pragma unroll
        for (int i = 0; i < 8; ++i)
            ss += bv[i].x * bv[i].x + bv[i].y * bv[i].y + bv[i].z * bv[i].z + bv[i].w * bv[i].w;
        ss += __shfl_xor(ss, 16);
        ss += __shfl_xor(ss, 32);
        const float s = rsqrtf(ss);

        f32x4 acc[4] = {};
        #pragma unroll
        for (int ks = 0; ks < 4; ++ks) {
            uint4 w;
            w.x = pack_bf16x2(bv[2 * ks].x * s,     bv[2 * ks].y * s);
            w.y = pack_bf16x2(bv[2 * ks].z * s,     bv[2 * ks].w * s);
            w.z = pack_bf16x2(bv[2 * ks + 1].x * s, bv[2 * ks + 1].y * s);
            w.w = pack_bf16x2(bv[2 * ks + 1].z * s, bv[2 * ks + 1].w * s);
            bf16x8 bfr = __builtin_bit_cast(bf16x8, w);
            #pragma unroll
            for (int mi = 0; mi < 4; ++mi)
                acc[mi] = __builtin_amdgcn_mfma_f32_16x16x32_bf16(
                    af[ks][mi], bfr, acc[mi], 0, 0, 0);
        }

        // C/D layout: col=lane&15, row=(lane>>4)*4+reg. Stores never waited.
        #pragma unroll
        for (int mi = 0; mi < 4; ++mi) {
            #pragma unroll
            for (int i = 0; i < 4; ++i) {
                int r = wm + mi * 16 + kq * 4 + i;
                int c = nj * 64 + wn + lr;
                obase[(size_t)r * OCOLS + c] = acc[mi][i];
            }
        }
    };

    // Main loop: 16 chunks, 2-stage register pipeline, no barriers.
    for (int nj = 0; nj < 16; nj += 2) {
        loadB(bvb, nj + 1);
        process(bva, nj);
        if (nj + 2 < 16) loadB(bva, nj + 2);
        process(bvb, nj + 1);
    }

    // Dustbin: col 1024 for this slab's rows; row 2048 once per batch.
    if (t < 128)
        obase[(size_t)t * OCOLS + N2] = 0.0f;
    if (ti == 15) {
        float* last = out + (size_t)b * OROWS * OCOLS + (size_t)N3 * OCOLS;
        for (int c = t; c < OCOLS; c += 512) last[c] = 0.0f;
    }
}

extern "C" void kernel_launch(void* const* d_in, const int* in_sizes, int n_in,
                              void* d_out, int out_size, void* d_ws, size_t ws_size,
                              hipStream_t stream) {
    (void)in_sizes; (void)n_in; (void)out_size; (void)d_ws; (void)ws_size;
    const float* desc2d = (const float*)d_in[0];
    const float* desc3d = (const float*)d_in[2];
    float* out = (float*)d_out;

    fused_kernel<<<NB * (N3 / 128), 512, 0, stream>>>(desc2d, desc3d, out);
}

// Round 6
// 39.775 us; speedup vs baseline: 1.3394x; 1.3394x over previous
//
#include <hip/hip_runtime.h>
#include <hip/hip_bf16.h>

// Problem constants (from reference): B=16, N2=1024, N3=2048, D=128
#define NB   16
#define N2   1024
#define N3   2048
#define DD   128
#define OROWS (N3 + 1)   // 2049
#define OCOLS (N2 + 1)   // 1025

typedef __attribute__((ext_vector_type(8))) __bf16 bf16x8;
typedef __attribute__((ext_vector_type(4))) float  f32x4;

// Pack two f32 into one u32 of 2x bf16 (RNE). a -> low half, b -> high half.
static __device__ __forceinline__ unsigned pack_bf16x2(float a, float b) {
    unsigned ua = __float_as_uint(a);
    ua = (ua + 0x7FFF + ((ua >> 16) & 1)) >> 16;
    unsigned ub = __float_as_uint(b);
    ub = (ub + 0x7FFF + ((ub >> 16) & 1)) & 0xFFFF0000u;
    return ua | ub;
}

// Normalize d2 only -> bf16 ws (row-major [NB*N2][128]).
__global__ void normalize_d2(const float* __restrict__ d2,
                             unsigned short* __restrict__ ws) {
    const int row = blockIdx.x * 8 + (threadIdx.x >> 5);
    const int l   = threadIdx.x & 31;
    const float4 v = *reinterpret_cast<const float4*>(d2 + (size_t)row * DD + l * 4);
    float ss = v.x * v.x + v.y * v.y + v.z * v.z + v.w * v.w;
    #pragma unroll
    for (int off = 16; off; off >>= 1) ss += __shfl_xor(ss, off);
    const float s = rsqrtf(ss);
    ushort4 o;
    o.x = (unsigned short)(pack_bf16x2(v.x * s, v.y * s) & 0xFFFF);
    o.y = (unsigned short)(pack_bf16x2(v.y * s, 0.f) & 0xFFFF);
    // (re-pack cleanly below to avoid confusion)
    unsigned w0 = pack_bf16x2(v.x * s, v.y * s);
    unsigned w1 = pack_bf16x2(v.z * s, v.w * s);
    uint2 w; w.x = w0; w.y = w1;
    *reinterpret_cast<uint2*>(ws + (size_t)row * DD + l * 4) = w;
}

// GEMM with fused A-normalize. One block = one 128(M) x 1024(N) output slab.
// Grid = 256 = 1 block/CU, bijective XCD swizzle.
// A: reg-stage f32 -> row norm -> bf16 -> swizzled LDS [0,32K) -> hoist to
//    registers (A LDS region dead afterwards, reused by the B ring).
// B: pre-normalized bf16 from ws, staged via global_load_lds (pre-swizzled
//    source) into a 3x16KB ring with PREFETCH DEPTH 2: loads for chunk j+2
//    issue in iter j, are waited at end of iter j+1 -> a full HBM-paced
//    iteration hides the load latency. In-loop s_waitcnt vmcnt(18) =
//    2 (next-next loads) + 16 (this iter's stores): output stores are never
//    drained in-loop; chunk j+1's loads are guaranteed retired (FIFO).
__global__ __launch_bounds__(512, 1)
void gemm_kernel(const float* __restrict__ d3,
                 const unsigned short* __restrict__ d2n,
                 float* __restrict__ out) {
    __shared__ __align__(16) char smem[49152];
    // ring region for chunk c: 16KB * ((c+2)%3). chunk0 -> @32K (disjoint
    // from A's [0,32K) during prologue); chunks 1,2 -> dead-A regions.

    const int hw  = blockIdx.x;
    const int blk = (hw & 7) * 32 + (hw >> 3);   // 8 XCDs x 32; 2 batches/XCD
    const int b   = blk >> 4;
    const int ti  = blk & 15;
    const int t   = threadIdx.x;

    const float* gA = d3 + (size_t)(b * N3 + ti * 128) * DD;
    const char*  gB = (const char*)d2n + ((size_t)(b * N2) << 8);  // 256 B/row

    auto stage = [&](int c) {   // 16 KB: 2 x 512thr x 16B, pre-swizzled source
        const char* src = gB + (size_t)c * 16384;
        char* dst = smem + 16384 * ((c + 2) % 3);
        #pragma unroll
        for (int it = 0; it < 2; ++it) {
            int o    = it * 8192 + t * 16;
            int row  = o >> 8;
            int scol = (o & 255) ^ ((row & 7) << 4);
            __builtin_amdgcn_global_load_lds(
                (const __attribute__((address_space(1))) void*)(src + row * 256 + scol),
                (__attribute__((address_space(3))) void*)(dst + o), 16, 0, 0);
        }
    };

    // ---- Prologue: A f32 loads + chunk-0 stage ----
    const int arow  = t >> 2;      // 0..127
    const int apart = t & 3;       // 32-f32 part
    float4 av[8];
    #pragma unroll
    for (int i = 0; i < 8; ++i)
        av[i] = *reinterpret_cast<const float4*>(gA + (size_t)arow * DD + apart * 32 + i * 4);
    stage(0);

    // A: norm (4 lanes/row) -> bf16 -> swizzled LDS (st-16x32).
    {
        float ss = 0.f;
        #pragma unroll
        for (int i = 0; i < 8; ++i)
            ss += av[i].x * av[i].x + av[i].y * av[i].y + av[i].z * av[i].z + av[i].w * av[i].w;
        ss += __shfl_xor(ss, 1);
        ss += __shfl_xor(ss, 2);
        const float s = rsqrtf(ss);
        const int aswz = (arow & 7) << 4;
        #pragma unroll
        for (int j = 0; j < 4; ++j) {
            uint4 w;
            w.x = pack_bf16x2(av[2 * j].x * s,     av[2 * j].y * s);
            w.y = pack_bf16x2(av[2 * j].z * s,     av[2 * j].w * s);
            w.z = pack_bf16x2(av[2 * j + 1].x * s, av[2 * j + 1].y * s);
            w.w = pack_bf16x2(av[2 * j + 1].z * s, av[2 * j + 1].w * s);
            int colb = apart * 64 + j * 16;
            *reinterpret_cast<uint4*>(smem + arow * 256 + (colb ^ aswz)) = w;
        }
    }
    asm volatile("s_waitcnt vmcnt(0) lgkmcnt(0)" ::: "memory");
    __builtin_amdgcn_s_barrier();
    __builtin_amdgcn_sched_barrier(0);

    // ---- Hoist A fragments; then barrier so the B-ring may reuse A's LDS ----
    const int wid = t >> 6;
    const int l   = t & 63;
    const int wm  = (wid >> 2) * 64;
    const int wn  = (wid & 3) * 16;
    const int lr  = l & 15;
    const int kq  = l >> 4;
    const int sw  = (lr & 7) << 4;

    bf16x8 af[4][4];   // [ks][mi]
    #pragma unroll
    for (int ks = 0; ks < 4; ++ks) {
        const int kb = ks * 64 + kq * 16;
        #pragma unroll
        for (int mi = 0; mi < 4; ++mi) {
            int r = wm + mi * 16 + lr;
            af[ks][mi] = *reinterpret_cast<const bf16x8*>(smem + r * 256 + (kb ^ sw));
        }
    }
    asm volatile("s_waitcnt lgkmcnt(0)" ::: "memory");
    __builtin_amdgcn_s_barrier();
    __builtin_amdgcn_sched_barrier(0);

    float* obase = out + (size_t)b * OROWS * OCOLS + (size_t)(ti * 128) * OCOLS;

    // ---- Main loop: 16 chunks, 3-buffer ring, prefetch depth 2 ----
    for (int nj = 0; nj < 16; ++nj) {
        const char* bbuf = smem + 16384 * ((nj + 2) % 3);

        f32x4 acc[4] = {};
        #pragma unroll
        for (int ks = 0; ks < 4; ++ks) {
            const int kb = ks * 64 + kq * 16;
            bf16x8 bfr = *reinterpret_cast<const bf16x8*>(bbuf + (wn + lr) * 256 + (kb ^ sw));
            #pragma unroll
            for (int mi = 0; mi < 4; ++mi)
                acc[mi] = __builtin_amdgcn_mfma_f32_16x16x32_bf16(
                    af[ks][mi], bfr, acc[mi], 0, 0, 0);
        }

        // Prefetch: iter 0 issues chunks 1 AND 2 (fills the depth-2 pipe);
        // iters 1..13 issue chunk nj+2.
        if (nj == 0) { stage(1); stage(2); }
        else if (nj + 2 < 16) stage(nj + 2);

        // Stores (C/D: col=lane&15, row=(lane>>4)*4+reg); never drained.
        #pragma unroll
        for (int mi = 0; mi < 4; ++mi) {
            #pragma unroll
            for (int i = 0; i < 4; ++i) {
                int r = wm + mi * 16 + kq * 4 + i;
                int c = nj * 64 + wn + lr;
                obase[(size_t)r * OCOLS + c] = acc[mi][i];
            }
        }

        // FIFO wait: newest-18 = {2 loads(nj+2), 16 stores(nj)} -> chunk
        // nj+1's loads (issued a FULL iteration ago) are retired. At nj=14
        // no new loads were issued -> newest-16 = stores only.
        if (nj < 14) {
            asm volatile("s_waitcnt vmcnt(18)" ::: "memory");
            __builtin_amdgcn_s_barrier();
            __builtin_amdgcn_sched_barrier(0);
        } else if (nj == 14) {
            asm volatile("s_waitcnt vmcnt(16)" ::: "memory");
            __builtin_amdgcn_s_barrier();
            __builtin_amdgcn_sched_barrier(0);
        }
    }

    // Dustbin: col 1024 for this slab's rows; row 2048 once per batch.
    if (t < 128)
        obase[(size_t)t * OCOLS + N2] = 0.0f;
    if (ti == 15) {
        float* last = out + (size_t)b * OROWS * OCOLS + (size_t)N3 * OCOLS;
        for (int c = t; c < OCOLS; c += 512) last[c] = 0.0f;
    }
}

extern "C" void kernel_launch(void* const* d_in, const int* in_sizes, int n_in,
                              void* d_out, int out_size, void* d_ws, size_t ws_size,
                              hipStream_t stream) {
    (void)in_sizes; (void)n_in; (void)out_size; (void)ws_size;
    const float* desc2d = (const float*)d_in[0];
    const float* desc3d = (const float*)d_in[2];

    unsigned short* d2n = (unsigned short*)d_ws;   // [NB*N2][128] bf16 = 4 MB
    float* out = (float*)d_out;

    normalize_d2<<<(NB * N2) / 8, 256, 0, stream>>>(desc2d, d2n);
    gemm_kernel<<<NB * (N3 / 128), 512, 0, stream>>>(desc3d, d2n, out);
}